// Round 3
// baseline (430.294 us; speedup 1.0000x reference)
//
#include <hip/hip_runtime.h>

#define GROUPS 32
#define GROUP_SIZE 25
#define ROW_FLOATS 800          // 32 * 25
#define ROWS_PER_ITER 8         // 8 rows * 800 floats = 25.6 KB LDS
#define BLOCK 256

__global__ void zero_out_kernel(float* out) { out[0] = 0.0f; }

__global__ __launch_bounds__(BLOCK) void group_l2_sum_kernel(
    const float* __restrict__ w,
    const int* __restrict__ c_omega_p,
    float* __restrict__ out,
    int n_rows)
{
    __shared__ float lds[ROWS_PER_ITER * ROW_FLOATS];   // 6400 floats = 25.6 KB
    const int t = threadIdx.x;
    const int n_chunks = (n_rows + ROWS_PER_ITER - 1) / ROWS_PER_ITER;

    float acc = 0.0f;

    for (int chunk = blockIdx.x; chunk < n_chunks; chunk += gridDim.x) {
        const long long row0 = (long long)chunk * ROWS_PER_ITER;
        const int rows = min(ROWS_PER_ITER, n_rows - (int)row0);
        const int nf4 = rows * (ROW_FLOATS / 4);        // float4 count this chunk

        // --- coalesced global -> LDS staging (float4) ---
        const float4* __restrict__ src =
            (const float4*)(w + row0 * ROW_FLOATS);
        float4* dst = (float4*)lds;
        #pragma unroll
        for (int k = 0; k < 7; ++k) {                   // 7*256 = 1792 >= 1600
            int idx = t + k * BLOCK;
            if (idx < nf4) dst[idx] = src[idx];
        }
        __syncthreads();

        // --- one group per thread: row = t>>5, group = t&31 ---
        const int r = t >> 5;
        const int g = t & 31;
        if (r < rows) {
            const float* p = lds + r * ROW_FLOATS + g * GROUP_SIZE;
            float s = 0.0f;
            #pragma unroll
            for (int k = 0; k < GROUP_SIZE; ++k) {
                float v = p[k];
                s += v * v;
            }
            acc += sqrtf(s);
        }
        __syncthreads();                                 // before LDS overwrite
    }

    // --- block reduction: wave shuffle, then across the 4 waves ---
    #pragma unroll
    for (int off = 32; off > 0; off >>= 1)
        acc += __shfl_down(acc, off, 64);

    __shared__ float wave_sum[BLOCK / 64];
    if ((t & 63) == 0) wave_sum[t >> 6] = acc;
    __syncthreads();

    if (t == 0) {
        float tot = wave_sum[0] + wave_sum[1] + wave_sum[2] + wave_sum[3];
        float scale = 0.001f * (float)c_omega_p[0] / (float)n_rows;
        atomicAdd(out, tot * scale);
    }
}

extern "C" void kernel_launch(void* const* d_in, const int* in_sizes, int n_in,
                              void* d_out, int out_size, void* d_ws, size_t ws_size,
                              hipStream_t stream)
{
    const float* w = (const float*)d_in[0];
    const int* c_omega = (const int*)d_in[1];
    float* out = (float*)d_out;

    const int n_rows = in_sizes[0] / ROW_FLOATS;         // 100000
    const int n_chunks = (n_rows + ROWS_PER_ITER - 1) / ROWS_PER_ITER;
    int grid = n_chunks < 2048 ? n_chunks : 2048;

    zero_out_kernel<<<1, 1, 0, stream>>>(out);
    group_l2_sum_kernel<<<grid, BLOCK, 0, stream>>>(w, c_omega, out, n_rows);
}